// Round 1
// baseline (176.785 us; speedup 1.0000x reference)
//
#include <hip/hip_runtime.h>

typedef short bf16x8 __attribute__((ext_vector_type(8)));
typedef float f32x4 __attribute__((ext_vector_type(4)));
typedef unsigned short us4 __attribute__((ext_vector_type(4)));

#define MFMA16(a, b, c) __builtin_amdgcn_mfma_f32_16x16x32_bf16(a, b, c, 0, 0, 0)

__device__ __forceinline__ unsigned short f2bf(float f) {
    unsigned int u = __float_as_uint(f);
    u += 0x7FFFu + ((u >> 16) & 1u);   // round-to-nearest-even
    return (unsigned short)(u >> 16);
}

// ---------------- workspace layout (bytes) ----------------
#define WQT_OFF 0        // ushort[576*192]  W_qkv^T bf16, Q cols pre-scaled
#define WOT_OFF 221184   // ushort[192*192]  W_out^T  bf16
#define BQ_OFF  294912   // float[576]       b_qkv, Q part pre-scaled
// total 297216 bytes

__global__ void prep_kernel(const float* __restrict__ Wqkv,
                            const float* __restrict__ bqkv,
                            const float* __restrict__ Wout,
                            unsigned short* __restrict__ WqT,
                            unsigned short* __restrict__ WoT,
                            float* __restrict__ bq) {
    const float SCALE = 0.17677669529663687f;  // 1/sqrt(32)
    int i = blockIdx.x * 256 + threadIdx.x;
    if (i < 110592) {                       // W_qkv: [c][n] -> [n][c]
        int n = i / 192, c = i - n * 192;
        float v = Wqkv[c * 576 + n];
        if (n < 192) v *= SCALE;
        WqT[i] = f2bf(v);
    } else if (i < 147456) {                // W_out: [c][n] -> [n][c]
        int j = i - 110592;
        int n = j / 192, c = j - n * 192;
        WoT[j] = f2bf(Wout[c * 192 + n]);
    } else if (i < 148032) {
        int n = i - 147456;
        float v = bqkv[n];
        if (n < 192) v *= SCALE;
        bq[n] = v;
    }
}

// ---------------- LDS layout (ushort units) ----------------
// sX  [64][208] bf16 window input (aliased by sP in phase 2)
// sQK [64][392] bf16 Q(cols 0..191 scaled) | K(192..383)
// sVt [192][72] bf16 V transposed [c][t]
// sO  [64][208] bf16 attention output
// sRel float[2058] rel_params copy
#define OFF_X   0
#define OFF_P   0          // per-wave [16][72], aliases sX (dead after phase 1)
#define OFF_QK  13312
#define OFF_VT  38400
#define OFF_O   52224
#define OFF_RELF 65536     // float region starts here (ushort index)
#define SMEM_US 69652      // 139304 bytes total

__global__ __launch_bounds__(512, 2) void wmsa_kernel(
    const float* __restrict__ x, const float* __restrict__ rel,
    const float* __restrict__ bout,
    const unsigned short* __restrict__ WqT,
    const unsigned short* __restrict__ WoT,
    const float* __restrict__ bq, float* __restrict__ out) {
    __shared__ __align__(16) unsigned short smem[SMEM_US];
    float* sRel = (float*)&smem[OFF_RELF];

    const int tid = threadIdx.x;
    const int bw = blockIdx.x;
    const int b  = bw >> 9;
    const int w  = bw & 511;
    const int wz = w >> 6, wy = (w >> 3) & 7, wx = w & 7;

    // ---------- phase 0: load rel_params + x window (fp32 -> bf16 LDS) ----------
    for (int i = tid; i < 2058; i += 512) sRel[i] = rel[i];
    {
        int t = tid >> 3, q8 = tid & 7;           // 8 threads per token
        int tz = t >> 4, ty = (t >> 2) & 3, tx = t & 3;
        int gz = (wz * 4 + tz + 2) & 31;          // roll(-2) folded in
        int gy = (wy * 4 + ty + 2) & 31;
        int gx = (wx * 4 + tx + 2) & 31;
        const float* xp = x + ((((b * 32 + gz) * 32 + gy) * 32 + gx)) * 192;
#pragma unroll
        for (int k = 0; k < 6; ++k) {
            int c = (q8 << 2) + (k << 5);         // 4 floats, stride 32 across k
            float4 v = *(const float4*)(xp + c);
            us4 pk;
            pk[0] = f2bf(v.x); pk[1] = f2bf(v.y);
            pk[2] = f2bf(v.z); pk[3] = f2bf(v.w);
            *(us4*)&smem[OFF_X + t * 208 + c] = pk;
        }
    }
    __syncthreads();

    const int lane = tid & 63;
    const int wv   = tid >> 6;     // wave id 0..7
    const int g    = lane >> 4;    // quad id 0..3
    const int l15  = lane & 15;

    // ---------- phase 1: QKV = Xw @ WqkvT^T + bq  (64x576) ----------
    {
        bf16x8 afr[4][6];          // A fragments cached: 4 m-blocks x 6 k-iters
#pragma unroll
        for (int m = 0; m < 4; ++m)
#pragma unroll
            for (int kk = 0; kk < 6; ++kk)
                afr[m][kk] = *(const bf16x8*)&smem[OFF_X + (m * 16 + l15) * 208 + kk * 32 + g * 8];

        // wave wv handles n-blocks {wv, wv+8, wv+16, wv+24 (,wv+32)}; prefetch next B
        int nb = wv;
        float bias = bq[nb * 16 + l15];
        bf16x8 bfr[6];
        {
            const unsigned short* wp = WqT + (nb * 16 + l15) * 192 + g * 8;
#pragma unroll
            for (int kk = 0; kk < 6; ++kk) bfr[kk] = *(const bf16x8*)(wp + kk * 32);
        }
        while (true) {
            int nbN = nb + 8;
            bool more = (nbN < 36);
            bf16x8 bfrN[6];
            float biasN = 0.f;
            if (more) {
                biasN = bq[nbN * 16 + l15];
                const unsigned short* wp = WqT + (nbN * 16 + l15) * 192 + g * 8;
#pragma unroll
                for (int kk = 0; kk < 6; ++kk) bfrN[kk] = *(const bf16x8*)(wp + kk * 32);
            }
            int colg = nb * 16 + l15;
            bool isV = (nb >= 24);
#pragma unroll
            for (int m = 0; m < 4; ++m) {
                f32x4 acc = {bias, bias, bias, bias};
#pragma unroll
                for (int kk = 0; kk < 6; ++kk) acc = MFMA16(afr[m][kk], bfr[kk], acc);
                int row0 = m * 16 + g * 4;
                if (!isV) {                       // Q/K -> sQK[t][col]
#pragma unroll
                    for (int r = 0; r < 4; ++r)
                        smem[OFF_QK + (row0 + r) * 392 + colg] = f2bf(acc[r]);
                } else {                          // V -> sVt[c][t], 4 contiguous t
                    us4 pk;
#pragma unroll
                    for (int r = 0; r < 4; ++r) pk[r] = f2bf(acc[r]);
                    *(us4*)&smem[OFF_VT + (colg - 384) * 72 + row0] = pk;
                }
            }
            if (!more) break;
            nb = nbN;
            bias = biasN;
#pragma unroll
            for (int kk = 0; kk < 6; ++kk) bfr[kk] = bfrN[kk];
        }
    }
    __syncthreads();

    // ---------- phase 2: per (head, 16-row block) attention ----------
    const bool sz = (wz == 7), sy = (wy == 7), sx = (wx == 7);
    {
        const int qy = (l15 >> 2) & 3, qx = l15 & 3;
        for (int it = wv * 3; it < wv * 3 + 3; ++it) {
            int h = it >> 2, mb = it & 3;
            bf16x8 qf = *(const bf16x8*)&smem[OFF_QK + (mb * 16 + l15) * 392 + h * 32 + g * 8];
            f32x4 s[4];
#pragma unroll
            for (int f = 0; f < 4; ++f) {
                bf16x8 kf = *(const bf16x8*)&smem[OFF_QK + (f * 16 + l15) * 392 + 192 + h * 32 + g * 8];
                f32x4 z = {0.f, 0.f, 0.f, 0.f};
                s[f] = MFMA16(qf, kf, z);
            }
            // bias + shift mask.  p=(mb,g,r), q=(f,qy,qx)
#pragma unroll
            for (int f = 0; f < 4; ++f) {
                bool mz = sz && ((mb < 2) != (f < 2));
                bool my = sy && ((g < 2) != (qy < 2));
                int base = h * 343 + (mb - f + 3) * 49 + (g - qy + 3) * 7 + (3 - qx);
#pragma unroll
                for (int r = 0; r < 4; ++r) {
                    float v = s[f][r] + sRel[base + r];
                    bool mx = sx && ((r < 2) != (qx < 2));
                    s[f][r] = (mz | my | mx) ? -1e30f : v;
                }
            }
            // softmax per row (row = mb*16 + g*4 + r): reduce over f and 16 lanes
#pragma unroll
            for (int r = 0; r < 4; ++r) {
                float m0 = fmaxf(fmaxf(s[0][r], s[1][r]), fmaxf(s[2][r], s[3][r]));
#pragma unroll
                for (int d = 1; d < 16; d <<= 1) m0 = fmaxf(m0, __shfl_xor(m0, d, 64));
                float p0 = __expf(s[0][r] - m0);
                float p1 = __expf(s[1][r] - m0);
                float p2 = __expf(s[2][r] - m0);
                float p3 = __expf(s[3][r] - m0);
                float sm = p0 + p1 + p2 + p3;
#pragma unroll
                for (int d = 1; d < 16; d <<= 1) sm += __shfl_xor(sm, d, 64);
                float inv = 1.0f / sm;
                s[0][r] = p0 * inv; s[1][r] = p1 * inv;
                s[2][r] = p2 * inv; s[3][r] = p3 * inv;
            }
            // P -> per-wave LDS scratch (C-layout scatter), then A-frag reads
            unsigned short* pbase = &smem[OFF_P + wv * 1152];
#pragma unroll
            for (int f = 0; f < 4; ++f)
#pragma unroll
                for (int r = 0; r < 4; ++r)
                    pbase[(g * 4 + r) * 72 + f * 16 + l15] = f2bf(s[f][r]);
            // PV: O(16x32) = P(16x64) @ V(64x32)
            f32x4 o0 = {0.f, 0.f, 0.f, 0.f}, o1 = {0.f, 0.f, 0.f, 0.f};
#pragma unroll
            for (int kt = 0; kt < 2; ++kt) {
                bf16x8 pf = *(const bf16x8*)&pbase[l15 * 72 + kt * 32 + g * 8];
                bf16x8 v0 = *(const bf16x8*)&smem[OFF_VT + (h * 32 + l15) * 72 + kt * 32 + g * 8];
                bf16x8 v1 = *(const bf16x8*)&smem[OFF_VT + (h * 32 + 16 + l15) * 72 + kt * 32 + g * 8];
                o0 = MFMA16(pf, v0, o0);
                o1 = MFMA16(pf, v1, o1);
            }
#pragma unroll
            for (int r = 0; r < 4; ++r) {
                smem[OFF_O + (mb * 16 + g * 4 + r) * 208 + h * 32 + l15]      = f2bf(o0[r]);
                smem[OFF_O + (mb * 16 + g * 4 + r) * 208 + h * 32 + 16 + l15] = f2bf(o1[r]);
            }
        }
    }
    __syncthreads();

    // ---------- phase 3: out = O(64x192) @ WoutT^T + b_out, scatter to global ----------
    {
        int mw = wv >> 2, nq = wv & 3;   // 2 m-blocks x 3 n-blocks per wave
        bf16x8 ofr[2][6];
#pragma unroll
        for (int mi = 0; mi < 2; ++mi)
#pragma unroll
            for (int kk = 0; kk < 6; ++kk)
                ofr[mi][kk] = *(const bf16x8*)&smem[OFF_O + ((mw * 2 + mi) * 16 + l15) * 208 + kk * 32 + g * 8];
#pragma unroll
        for (int nbi = 0; nbi < 3; ++nbi) {
            int col = (nq + nbi * 4) * 16 + l15;
            float bo = bout[col];
            bf16x8 bfr[6];
            const unsigned short* wp = WoT + col * 192 + g * 8;
#pragma unroll
            for (int kk = 0; kk < 6; ++kk) bfr[kk] = *(const bf16x8*)(wp + kk * 32);
#pragma unroll
            for (int mi = 0; mi < 2; ++mi) {
                f32x4 acc = {bo, bo, bo, bo};
#pragma unroll
                for (int kk = 0; kk < 6; ++kk) acc = MFMA16(ofr[mi][kk], bfr[kk], acc);
                int m = mw * 2 + mi;                    // token t = m*16 + g*4 + r
                int gz = (wz * 4 + m + 2) & 31;         // roll(+2) folded in
                int gy = (wy * 4 + g + 2) & 31;
#pragma unroll
                for (int r = 0; r < 4; ++r) {
                    int gx = (wx * 4 + r + 2) & 31;
                    out[(((b * 32 + gz) * 32 + gy) * 32 + gx) * 192 + col] = acc[r];
                }
            }
        }
    }
}

extern "C" void kernel_launch(void* const* d_in, const int* in_sizes, int n_in,
                              void* d_out, int out_size, void* d_ws, size_t ws_size,
                              hipStream_t stream) {
    const float* x    = (const float*)d_in[0];
    const float* Wqkv = (const float*)d_in[1];
    const float* bqkv = (const float*)d_in[2];
    const float* rel  = (const float*)d_in[3];
    const float* Wout = (const float*)d_in[4];
    const float* bout = (const float*)d_in[5];

    unsigned short* WqT = (unsigned short*)((char*)d_ws + WQT_OFF);
    unsigned short* WoT = (unsigned short*)((char*)d_ws + WOT_OFF);
    float*          bq  = (float*)((char*)d_ws + BQ_OFF);
    float*          out = (float*)d_out;

    prep_kernel<<<579, 256, 0, stream>>>(Wqkv, bqkv, Wout, WqT, WoT, bq);
    wmsa_kernel<<<1024, 512, 0, stream>>>(x, rel, bout, WqT, WoT, bq, out);
}